// Round 12
// baseline (617.327 us; speedup 1.0000x reference)
//
#include <hip/hip_runtime.h>
#include <hip/hip_bf16.h>

typedef unsigned short u16;
typedef __attribute__((ext_vector_type(4))) unsigned short u16x4;
typedef __attribute__((ext_vector_type(8))) unsigned short u16x8;
typedef __attribute__((ext_vector_type(8))) short bf16x8;
typedef __attribute__((ext_vector_type(4))) float f32x4;

__device__ __forceinline__ u16 f2bs(float f) {
    union { float f; unsigned int u; } x; x.f = f;
    unsigned int r = x.u + 0x7FFFu + ((x.u >> 16) & 1u);   // RNE
    return (u16)(r >> 16);
}
__device__ __forceinline__ float bs2f(u16 u) {
    union { unsigned int u; float f; } x; x.u = ((unsigned int)u) << 16; return x.f;
}
__device__ __forceinline__ float lrelu(float e) { return e >= 0.f ? e : 0.2f * e; }

// packed f32->bf16 RNE, 2 elements per VALU op (gfx950). Low half = src0.
__device__ __forceinline__ unsigned cvtpk(float lo, float hi) {
    unsigned r;
    asm("v_cvt_pk_bf16_f32 %0, %1, %2" : "=v"(r) : "v"(lo), "v"(hi));
    return r;
}

// async global->LDS, 16B/lane; lds dest is wave-uniform base (HW adds lane*16)
__device__ __forceinline__ void glds16(const void* g, void* l) {
    __builtin_amdgcn_global_load_lds(
        (const __attribute__((address_space(1))) unsigned int*)g,
        (__attribute__((address_space(3))) unsigned int*)l, 16, 0, 0);
}

// ---------------- CSR build ----------------
__global__ void deg_kernel(const int* __restrict__ dst, int* __restrict__ deg, int E) {
    int i = blockIdx.x * 256 + threadIdx.x;
    if (i < E) atomicAdd(&deg[dst[i]], 1);
}

// hierarchical scan: local (1024/block) -> carry scan -> fixup
__global__ __launch_bounds__(1024) void scan_local(const int* __restrict__ deg,
        int* __restrict__ ptr, int* __restrict__ bsum, int N) {
    __shared__ int wsum[16];
    const int t = threadIdx.x, i = blockIdx.x * 1024 + t;
    const int lane = t & 63, w = t >> 6;
    int v = (i < N) ? deg[i] : 0;
    int x = v;
    #pragma unroll
    for (int off = 1; off < 64; off <<= 1) { int y = __shfl_up(x, off); if (lane >= off) x += y; }
    if (lane == 63) wsum[w] = x;
    __syncthreads();
    if (w == 0) {
        int s = (lane < 16) ? wsum[lane] : 0;
        #pragma unroll
        for (int off = 1; off < 16; off <<= 1) { int y = __shfl_up(s, off); if (lane >= off) s += y; }
        if (lane < 16) wsum[lane] = s;
    }
    __syncthreads();
    int incl = x + (w > 0 ? wsum[w - 1] : 0);
    if (i < N) ptr[i + 1] = incl;            // local inclusive; fixed by scan_final
    if (t == 0) bsum[blockIdx.x] = wsum[15];
}

__global__ __launch_bounds__(64) void scan_carry(int* __restrict__ bsum, int nb) {
    int t = threadIdx.x;
    int v = (t < nb) ? bsum[t] : 0;
    int x = v;
    #pragma unroll
    for (int off = 1; off < 64; off <<= 1) { int y = __shfl_up(x, off); if (t >= off) x += y; }
    if (t < nb) bsum[t] = x - v;             // exclusive
}

__global__ __launch_bounds__(1024) void scan_final(const int* __restrict__ deg,
        int* __restrict__ ptr, int* __restrict__ cur, const int* __restrict__ bsum, int N) {
    int i = blockIdx.x * 1024 + threadIdx.x;
    if (i == 0) ptr[0] = 0;
    if (i < N) {
        int p = ptr[i + 1] + bsum[blockIdx.x];
        ptr[i + 1] = p;
        cur[i] = p - deg[i];
    }
}

__global__ void fill_kernel(const int* __restrict__ src, const int* __restrict__ dst,
        int* __restrict__ cur, int* __restrict__ csr, int E) {
    int i = blockIdx.x * 256 + threadIdx.x;
    if (i < E) { int p = atomicAdd(&cur[dst[i]], 1); csr[p] = src[i]; }
}

// ---------------- graph boundary index (batch is sorted) ----------------
__global__ void bounds_kernel(const int* __restrict__ batch, int* __restrict__ gstart,
        int N, int G) {
    int i = blockIdx.x * 256 + threadIdx.x;
    if (i > N) return;
    if (i == 0) {
        int b0 = batch[0];
        for (int g = 0; g <= b0; g++) gstart[g] = 0;
    } else if (i == N) {
        int bl = batch[N - 1];
        for (int g = bl + 1; g <= G; g++) gstart[g] = N;
    } else {
        int b = batch[i], bp = batch[i - 1];
        for (int g = bp + 1; g <= b; g++) gstart[g] = i;
    }
}

// ---------------- weight transpose: fp32 W[K][Nn] -> bf16 Wt[Nn][KT] (zero-pad k>=K) ----
__global__ void transpose_w(const float* __restrict__ W, u16* __restrict__ Wt,
        int K, int Nn, int KT) {
    int idx = blockIdx.x * 256 + threadIdx.x;
    if (idx >= Nn * KT) return;
    int n = idx / KT, k = idx - n * KT;
    Wt[(size_t)n * KT + k] = (k < K) ? f2bs(W[(size_t)k * Nn + n]) : (u16)0;
}

// ---------------- x tail pack: xtail[n][j] = x[n][768+j] (j<7), else 0 --------------
__global__ __launch_bounds__(256) void tail_kernel(const float* __restrict__ x,
        float* __restrict__ xtail, int N) {
    int idx = blockIdx.x * 256 + threadIdx.x;
    if (idx >= N * 32) return;
    int n = idx >> 5, j = idx & 31;
    xtail[idx] = (768 + j < 775) ? x[(size_t)n * 775 + 768 + j] : 0.f;
}

// ---------------- layer-1 GEMM: C[M,256] bf16 = fp32 A[M,775] @ Wt^T ----------------
// m97 structure + TRIPLE-BUFFERED glds with counted vmcnt + raw s_barrier (T3+T4):
// tile t+1 stays in flight ACROSS the barrier (vmcnt(6), never 0 in the loop), so
// each tile's loads get ~2 compute phases (~800cy) to land. One raw barrier/step.
// Round 10's __syncthreads emitted vmcnt(0) -> drained the fresh stage every step.
// Hazards: WAR on buf[(kt+2)%3] protected by barrier (all waves past compute(kt-1));
// RAW on buf[kt%3] by per-wave vmcnt(6) (6 = loads/stage/wave) + barrier.
// fp32 A via width-16 glds; last K-step reads pre-packed zero-padded Atail[N][32];
// cvt to bf16 at fragment read (v_cvt_pk_bf16_f32, RNE). Swizzle as round 8/10.
__global__ __launch_bounds__(256) void gemm_glds_f32(
        const float* __restrict__ A, int lda, int M,
        const float* __restrict__ Atail,
        const u16* __restrict__ B, int ldb,
        u16* __restrict__ C, int ldc) {
    __shared__ float Aldsf[3][128][32];
    __shared__ u16   Blds[3][128][32];
    const int t = threadIdx.x;
    const int col0 = blockIdx.x * 128;
    const int row0 = blockIdx.y * 128;
    const int wid = t >> 6, lane = t & 63;
    const int wm = wid >> 1, wn = wid & 1;
    const int quad = lane >> 4, l16 = lane & 15;

    f32x4 acc[4][4];
    f32x4 z = {0.f, 0.f, 0.f, 0.f};
    #pragma unroll
    for (int i = 0; i < 4; i++)
        #pragma unroll
        for (int j = 0; j < 4; j++) acc[i][j] = z;

    const int trb = wid * 32 + (lane >> 2);   // B staging row base
    const int arl = lane >> 3;                // A staging: row within 8-row chunk
    const int asg = lane & 7;                 // A staging: 16B group

    auto stage = [&](int buf, int kt) {       // 6 glds16 per lane per call
        const int k0 = kt << 5;
        #pragma unroll
        for (int c = 0; c < 2; c++) {
            const int tr = trb + c * 16;
            const int ks = ((lane & 3) ^ ((tr >> 1) & 3)) * 8;
            glds16(B + (size_t)(col0 + tr) * ldb + k0 + ks, &Blds[buf][wid * 32 + c * 16][0]);
        }
        #pragma unroll
        for (int c = 0; c < 4; c++) {
            const int rt = wid * 32 + c * 8 + arl;          // tile row
            int gra = row0 + rt; if (gra > M - 1) gra = M - 1;
            const int sg = (asg ^ ((rt & 3) << 1)) * 4;     // source float offset
            const float* src = (kt < 24) ? (A + (size_t)gra * lda + k0 + sg)
                                         : (Atail + (size_t)gra * 32 + sg);
            glds16(src, &Aldsf[buf][wid * 32 + c * 8][0]);
        }
    };
    auto compute = [&](int buf) {
        bf16x8 af[4], bfr[4];
        #pragma unroll
        for (int it = 0; it < 4; it++) {
            const int r = wm * 64 + it * 16 + l16;
            const int go = ((2 * quad) ^ ((r & 3) << 1)) * 4;  // float offset of k-chunk 2q
            const f32x4 lo = *(const f32x4*)&Aldsf[buf][r][go];
            const f32x4 hi = *(const f32x4*)&Aldsf[buf][r][go + 4];
            union { unsigned u[4]; bf16x8 v; } uu;
            uu.u[0] = cvtpk(lo[0], lo[1]);
            uu.u[1] = cvtpk(lo[2], lo[3]);
            uu.u[2] = cvtpk(hi[0], hi[1]);
            uu.u[3] = cvtpk(hi[2], hi[3]);
            af[it] = uu.v;
        }
        #pragma unroll
        for (int jt = 0; jt < 4; jt++) {
            const int r = wn * 64 + jt * 16 + l16;
            bfr[jt] = *(const bf16x8*)&Blds[buf][r][(quad ^ ((r >> 1) & 3)) * 8];
        }
        #pragma unroll
        for (int it = 0; it < 4; it++)
            #pragma unroll
            for (int jt = 0; jt < 4; jt++)
                acc[it][jt] = __builtin_amdgcn_mfma_f32_16x16x32_bf16(af[it], bfr[jt], acc[it][jt], 0, 0, 0);
    };

    const int kTiles = 25;                    // 24 full from A + 1 from Atail
    stage(0, 0);
    stage(1, 1);
    for (int kt = 0; kt < kTiles - 1; ++kt) {
        asm volatile("s_waitcnt vmcnt(6)" ::: "memory");   // tile kt ready (mine)
        __builtin_amdgcn_sched_barrier(0);
        __builtin_amdgcn_s_barrier();                      // everyone ready + compute(kt-1) done
        __builtin_amdgcn_sched_barrier(0);
        if (kt + 2 < kTiles) stage((kt + 2) % 3, kt + 2);  // overwrites buf read at kt-1: safe
        compute(kt % 3);
    }
    asm volatile("s_waitcnt vmcnt(0)" ::: "memory");       // final tile: drain
    __builtin_amdgcn_sched_barrier(0);
    __builtin_amdgcn_s_barrier();
    __builtin_amdgcn_sched_barrier(0);
    compute((kTiles - 1) % 3);

    #pragma unroll
    for (int it = 0; it < 4; it++) {
        int gr0 = row0 + wm * 64 + it * 16 + quad * 4;
        #pragma unroll
        for (int jt = 0; jt < 4; jt++) {
            int gc = col0 + wn * 64 + jt * 16 + l16;
            #pragma unroll
            for (int r = 0; r < 4; r++) {
                int gr = gr0 + r;
                if (gr < M) C[(size_t)gr * ldc + gc] = f2bs(acc[it][jt][r]);
            }
        }
    }
}

// ---------------- GEMM: C[M,256] bf16 = A[M,K]bf16 @ Wt^T (layer 2) ----------------
// Same triple-buffered counted-vmcnt pipeline, bf16 A (4 glds/stage -> vmcnt(4)).
__global__ __launch_bounds__(256) void gemm_glds(
        const u16* __restrict__ A, int lda, int M, int K,
        const u16* __restrict__ B, int ldb,
        u16* __restrict__ C, int ldc) {
    __shared__ u16 Alds[3][128][32];
    __shared__ u16 Blds[3][128][32];
    const int t = threadIdx.x;
    const int col0 = blockIdx.x * 128;
    const int row0 = blockIdx.y * 128;
    const int wid = t >> 6, lane = t & 63;
    const int wm = wid >> 1, wn = wid & 1;
    const int quad = lane >> 4, l16 = lane & 15;

    f32x4 acc[4][4];
    f32x4 z = {0.f, 0.f, 0.f, 0.f};
    #pragma unroll
    for (int i = 0; i < 4; i++)
        #pragma unroll
        for (int j = 0; j < 4; j++) acc[i][j] = z;

    const int trb = wid * 32 + (lane >> 2);

    auto stage = [&](int buf, int kt) {       // 4 glds16 per lane per call
        const int k0 = kt << 5;
        #pragma unroll
        for (int c = 0; c < 2; c++) {
            const int tr = trb + c * 16;
            const int ks = ((lane & 3) ^ ((tr >> 1) & 3)) * 8;   // swizzled source chunk
            int gra = row0 + tr; if (gra > M - 1) gra = M - 1;   // clamp: junk rows unused
            glds16(A + (size_t)gra * lda + k0 + ks, &Alds[buf][wid * 32 + c * 16][0]);
            glds16(B + (size_t)(col0 + tr) * ldb + k0 + ks, &Blds[buf][wid * 32 + c * 16][0]);
        }
    };
    auto compute = [&](int buf) {
        bf16x8 af[4], bfr[4];
        #pragma unroll
        for (int it = 0; it < 4; it++) {
            const int r = wm * 64 + it * 16 + l16;
            af[it] = *(const bf16x8*)&Alds[buf][r][(quad ^ ((r >> 1) & 3)) * 8];
        }
        #pragma unroll
        for (int jt = 0; jt < 4; jt++) {
            const int r = wn * 64 + jt * 16 + l16;
            bfr[jt] = *(const bf16x8*)&Blds[buf][r][(quad ^ ((r >> 1) & 3)) * 8];
        }
        #pragma unroll
        for (int it = 0; it < 4; it++)
            #pragma unroll
            for (int jt = 0; jt < 4; jt++)
                acc[it][jt] = __builtin_amdgcn_mfma_f32_16x16x32_bf16(af[it], bfr[jt], acc[it][jt], 0, 0, 0);
    };

    const int kTiles = K >> 5;
    stage(0, 0);
    stage(1, 1);
    for (int kt = 0; kt < kTiles - 1; ++kt) {
        asm volatile("s_waitcnt vmcnt(4)" ::: "memory");
        __builtin_amdgcn_sched_barrier(0);
        __builtin_amdgcn_s_barrier();
        __builtin_amdgcn_sched_barrier(0);
        if (kt + 2 < kTiles) stage((kt + 2) % 3, kt + 2);
        compute(kt % 3);
    }
    asm volatile("s_waitcnt vmcnt(0)" ::: "memory");
    __builtin_amdgcn_sched_barrier(0);
    __builtin_amdgcn_s_barrier();
    __builtin_amdgcn_sched_barrier(0);
    compute((kTiles - 1) % 3);

    #pragma unroll
    for (int it = 0; it < 4; it++) {
        int gr0 = row0 + wm * 64 + it * 16 + quad * 4;
        #pragma unroll
        for (int jt = 0; jt < 4; jt++) {
            int gc = col0 + wn * 64 + jt * 16 + l16;
            #pragma unroll
            for (int r = 0; r < 4; r++) {
                int gr = gr0 + r;
                if (gr < M) C[(size_t)gr * ldc + gc] = f2bs(acc[it][jt][r]);
            }
        }
    }
}

// GEMM for layer3: C[M,32] fp32 = A[M,256]bf16 @ Wt3^T (h3 stays fp32 — tiny)
__global__ __launch_bounds__(256) void gemm32(
        const u16* __restrict__ A, int lda, int M, int K,
        const u16* __restrict__ B, int ldb, float* __restrict__ C) {
    __shared__ u16 Alds[128][40];
    __shared__ u16 Blds[32][40];
    const int t = threadIdx.x;
    const int row0 = blockIdx.x * 128;
    const int wid = t >> 6, lane = t & 63;
    const int quad = lane >> 4, l16 = lane & 15;
    f32x4 acc[2][2];
    f32x4 z = {0.f, 0.f, 0.f, 0.f};
    acc[0][0] = z; acc[0][1] = z; acc[1][0] = z; acc[1][1] = z;
    const int kTiles = K >> 5;
    for (int kt = 0; kt < kTiles; ++kt) {
        const int k0 = kt << 5;
        #pragma unroll
        for (int c = 0; c < 2; c++) {
            int ch = t + c * 256;
            int r = ch >> 2, cp = (ch & 3) * 8;
            int gr = row0 + r;
            u16x8 v = {0,0,0,0,0,0,0,0};
            if (gr < M) v = *(const u16x8*)(A + (size_t)gr * lda + k0 + cp);
            *(u16x8*)&Alds[r][cp] = v;
        }
        if (t < 128) {
            int r = t >> 2, cp = (t & 3) * 8;
            *(u16x8*)&Blds[r][cp] = *(const u16x8*)(B + (size_t)r * ldb + k0 + cp);
        }
        __syncthreads();
        bf16x8 af[2], bfr[2];
        #pragma unroll
        for (int it = 0; it < 2; it++) af[it] = *(const bf16x8*)&Alds[wid * 32 + it * 16 + l16][quad * 8];
        #pragma unroll
        for (int jt = 0; jt < 2; jt++) bfr[jt] = *(const bf16x8*)&Blds[jt * 16 + l16][quad * 8];
        #pragma unroll
        for (int it = 0; it < 2; it++)
            #pragma unroll
            for (int jt = 0; jt < 2; jt++)
                acc[it][jt] = __builtin_amdgcn_mfma_f32_16x16x32_bf16(af[it], bfr[jt], acc[it][jt], 0, 0, 0);
        __syncthreads();
    }
    #pragma unroll
    for (int it = 0; it < 2; it++) {
        int gr0 = row0 + wid * 32 + it * 16 + quad * 4;
        #pragma unroll
        for (int jt = 0; jt < 2; jt++) {
            int gc = jt * 16 + l16;
            #pragma unroll
            for (int r = 0; r < 4; r++) {
                int gr = gr0 + r;
                if (gr < M) C[(size_t)gr * 32 + gc] = acc[it][jt][r];
            }
        }
    }
}

// ---------------- attention scalars (H=4, C=64), bf16 h: one wave/node, 8B loads ----
__global__ __launch_bounds__(256) void al_kernel(const u16* __restrict__ h,
        const float* __restrict__ a_s, const float* __restrict__ a_d,
        float* __restrict__ als, float* __restrict__ ald, int N) {
    const int t = threadIdx.x, wid = t >> 6, lane = t & 63;
    const f32x4 as4 = *(const f32x4*)&a_s[lane * 4];
    const f32x4 ad4 = *(const f32x4*)&a_d[lane * 4];
    #pragma unroll
    for (int u = 0; u < 2; u++) {
        const int n = blockIdx.x * 8 + wid * 2 + u;
        if (n >= N) return;
        const u16x4 hv = *(const u16x4*)&h[(size_t)n * 256 + lane * 4];
        float ps = 0.f, pd = 0.f;
        #pragma unroll
        for (int c = 0; c < 4; c++) {
            const float f = bs2f(hv[c]);
            ps = fmaf(f, as4[c], ps);
            pd = fmaf(f, ad4[c], pd);
        }
        #pragma unroll
        for (int off = 8; off >= 1; off >>= 1) {
            ps += __shfl_xor(ps, off, 16);
            pd += __shfl_xor(pd, off, 16);
        }
        if ((lane & 15) == 0) {
            als[n * 4 + (lane >> 4)] = ps;
            ald[n * 4 + (lane >> 4)] = pd;
        }
    }
}

__global__ __launch_bounds__(256) void al3_kernel(const float* __restrict__ h3,
        const float* __restrict__ a_s, const float* __restrict__ a_d,
        float* __restrict__ als, float* __restrict__ ald, int N) {
    int t = threadIdx.x, wid = t >> 6, lane = t & 63;
    int c = lane & 31, half = lane >> 5;
    float as = a_s[c], ad = a_d[c];
    int n = blockIdx.x * 8 + wid * 2 + half;
    if (n >= N) return;
    float hv = h3[(size_t)n * 32 + c];
    float ps = hv * as, pd = hv * ad;
    for (int off = 16; off >= 1; off >>= 1) { ps += __shfl_down(ps, off, 32); pd += __shfl_down(pd, off, 32); }
    if (c == 0) { als[n] = ps; ald[n] = pd; }
}

// ---------------- softmax-aggregation (H=4, C=64): one wave per node, bf16 h ----------------
// Single pass (deg<=64): e in registers, (s,alpha) staged in LDS once.
// Gather: 16B/lane, 32 lanes per neighbor row; halves own alternate edges ->
// 8 independent loads in flight per wave. Streaming fallback for deg>64.
__global__ __launch_bounds__(256) void agg_kernel(const u16* __restrict__ hbuf,
        const float* __restrict__ als, const float* __restrict__ ald,
        const int* __restrict__ ptr, const int* __restrict__ csr,
        const float* __restrict__ bias, u16* __restrict__ act, int N) {
    __shared__ float al_lds[4][64][4];
    __shared__ int   s_lds[4][64];
    const int t = threadIdx.x, wid = t >> 6, lane = t & 63;
    const int i = blockIdx.x * 4 + wid;
    if (i >= N) return;
    const int start = ptr[i], end = ptr[i + 1];
    const int deg = end - start;
    const int col8 = lane & 31;          // which 8-feature chunk of the 256-wide row
    const int half = lane >> 5;
    const int head8 = col8 >> 3;         // head owning this lane's 8 features

    const f32x4 aldv = *(const f32x4*)&ald[(size_t)i * 4];
    const f32x4 alsv = *(const f32x4*)&als[(size_t)i * 4];
    f32x4 eself;
    #pragma unroll
    for (int hh = 0; hh < 4; hh++) eself[hh] = lrelu(alsv[hh] + aldv[hh]);

    float acc[8];
    f32x4 mx, inv;

    if (deg <= 64) {
        // ---- single-pass softmax ----
        int sreg = 0;
        f32x4 ev;
        #pragma unroll
        for (int hh = 0; hh < 4; hh++) ev[hh] = -1e30f;
        if (lane < deg) {
            sreg = csr[start + lane];
            const f32x4 a = *(const f32x4*)&als[(size_t)sreg * 4];
            #pragma unroll
            for (int hh = 0; hh < 4; hh++) ev[hh] = lrelu(a[hh] + aldv[hh]);
        }
        #pragma unroll
        for (int hh = 0; hh < 4; hh++) mx[hh] = fmaxf(eself[hh], ev[hh]);
        #pragma unroll
        for (int off = 32; off >= 1; off >>= 1) {
            #pragma unroll
            for (int hh = 0; hh < 4; hh++) mx[hh] = fmaxf(mx[hh], __shfl_xor(mx[hh], off));
        }
        f32x4 sm, av;
        #pragma unroll
        for (int hh = 0; hh < 4; hh++) {
            av[hh] = (lane < deg) ? expf(ev[hh] - mx[hh]) : 0.f;
            sm[hh] = av[hh] + ((lane == 0) ? expf(eself[hh] - mx[hh]) : 0.f);
        }
        #pragma unroll
        for (int off = 32; off >= 1; off >>= 1) {
            #pragma unroll
            for (int hh = 0; hh < 4; hh++) sm[hh] += __shfl_xor(sm[hh], off);
        }
        #pragma unroll
        for (int hh = 0; hh < 4; hh++) inv[hh] = 1.f / (sm[hh] + 1e-16f);
        #pragma unroll
        for (int hh = 0; hh < 4; hh++) av[hh] *= inv[hh];
        *(f32x4*)&al_lds[wid][lane][0] = av;
        s_lds[wid][lane] = sreg;

        // ---- gather: 16B/lane, halves interleave edges ----
        const u16x8 hrs = *(const u16x8*)&hbuf[(size_t)i * 256 + col8 * 8];
        const float aself = expf(eself[head8] - mx[head8]) * inv[head8];
        #pragma unroll
        for (int c = 0; c < 8; c++) acc[c] = (half == 0) ? aself * bs2f(hrs[c]) : 0.f;

        int k = half;
        for (; k + 6 < deg; k += 8) {
            const int s0 = s_lds[wid][k],     s1 = s_lds[wid][k + 2];
            const int s2 = s_lds[wid][k + 4], s3 = s_lds[wid][k + 6];
            const float a0 = al_lds[wid][k][head8],     a1 = al_lds[wid][k + 2][head8];
            const float a2 = al_lds[wid][k + 4][head8], a3 = al_lds[wid][k + 6][head8];
            const u16x8 h0 = *(const u16x8*)&hbuf[(size_t)s0 * 256 + col8 * 8];
            const u16x8 h1 = *(const u16x8*)&hbuf[(size_t)s1 * 256 + col8 * 8];
            const u16x8 h2 = *(const u16x8*)&hbuf[(size_t)s2 * 256 + col8 * 8];
            const u16x8 h3v = *(const u16x8*)&hbuf[(size_t)s3 * 256 + col8 * 8];
            #pragma unroll
            for (int c = 0; c < 8; c++) {
                acc[c] = fmaf(a0, bs2f(h0[c]), acc[c]);
                acc[c] = fmaf(a1, bs2f(h1[c]), acc[c]);
                acc[c] = fmaf(a2, bs2f(h2[c]), acc[c]);
                acc[c] = fmaf(a3, bs2f(h3v[c]), acc[c]);
            }
        }
        for (; k < deg; k += 2) {
            const int s = s_lds[wid][k];
            const float a = al_lds[wid][k][head8];
            const u16x8 hr = *(const u16x8*)&hbuf[(size_t)s * 256 + col8 * 8];
            #pragma unroll
            for (int c = 0; c < 8; c++) acc[c] = fmaf(a, bs2f(hr[c]), acc[c]);
        }
    } else {
        // ---- streaming fallback (rare) ----
        mx = eself;
        for (int j = start + lane; j < end; j += 64) {
            int s = csr[j];
            const f32x4 a = *(const f32x4*)&als[(size_t)s * 4];
            #pragma unroll
            for (int hh = 0; hh < 4; hh++) mx[hh] = fmaxf(mx[hh], lrelu(a[hh] + aldv[hh]));
        }
        #pragma unroll
        for (int off = 32; off >= 1; off >>= 1) {
            #pragma unroll
            for (int hh = 0; hh < 4; hh++) mx[hh] = fmaxf(mx[hh], __shfl_xor(mx[hh], off));
        }
        f32x4 sm;
        #pragma unroll
        for (int hh = 0; hh < 4; hh++) sm[hh] = (lane == 0) ? expf(eself[hh] - mx[hh]) : 0.f;
        for (int j = start + lane; j < end; j += 64) {
            int s = csr[j];
            const f32x4 a = *(const f32x4*)&als[(size_t)s * 4];
            #pragma unroll
            for (int hh = 0; hh < 4; hh++) sm[hh] += expf(lrelu(a[hh] + aldv[hh]) - mx[hh]);
        }
        #pragma unroll
        for (int off = 32; off >= 1; off >>= 1) {
            #pragma unroll
            for (int hh = 0; hh < 4; hh++) sm[hh] += __shfl_xor(sm[hh], off);
        }
        #pragma unroll
        for (int hh = 0; hh < 4; hh++) inv[hh] = 1.f / (sm[hh] + 1e-16f);

        const u16x8 hrs = *(const u16x8*)&hbuf[(size_t)i * 256 + col8 * 8];
        const float aself = expf(eself[head8] - mx[head8]) * inv[head8];
        #pragma unroll
        for (int c = 0; c < 8; c++) acc[c] = (half == 0) ? aself * bs2f(hrs[c]) : 0.f;

        for (int base = start; base < end; base += 64) {
            const int n64 = min(64, end - base);
            const int j = base + lane;
            int sreg = 0;
            if (j < end) {
                sreg = csr[j];
                const f32x4 a = *(const f32x4*)&als[(size_t)sreg * 4];
                f32x4 alpha;
                #pragma unroll
                for (int hh = 0; hh < 4; hh++)
                    alpha[hh] = expf(lrelu(a[hh] + aldv[hh]) - mx[hh]) * inv[hh];
                *(f32x4*)&al_lds[wid][lane][0] = alpha;
            }
            s_lds[wid][lane] = sreg;
            for (int k = half; k < n64; k += 2) {
                const int s = s_lds[wid][k];
                const float a = al_lds[wid][k][head8];
                const u16x8 hr = *(const u16x8*)&hbuf[(size_t)s * 256 + col8 * 8];
                #pragma unroll
                for (int c = 0; c < 8; c++) acc[c] = fmaf(a, bs2f(hr[c]), acc[c]);
            }
        }
    }

    // combine halves, bias + ReLU, 16B store by half 0
    #pragma unroll
    for (int c = 0; c < 8; c++) acc[c] += __shfl_down(acc[c], 32);
    if (half == 0) {
        const f32x4 bv0 = *(const f32x4*)&bias[col8 * 8];
        const f32x4 bv1 = *(const f32x4*)&bias[col8 * 8 + 4];
        u16x8 o;
        #pragma unroll
        for (int c = 0; c < 4; c++) o[c] = f2bs(fmaxf(acc[c] + bv0[c], 0.f));
        #pragma unroll
        for (int c = 4; c < 8; c++) o[c] = f2bs(fmaxf(acc[c] + bv1[c - 4], 0.f));
        *(u16x8*)&act[(size_t)i * 256 + col8 * 8] = o;
    }
}

// ---------------- layer-3 aggregation (H=1, C=32): one wave/node, halves split edges ----
__global__ __launch_bounds__(256) void agg3_kernel(const float* __restrict__ h3,
        const float* __restrict__ als, const float* __restrict__ ald,
        const int* __restrict__ ptr, const int* __restrict__ csr,
        const float* __restrict__ bias, float* __restrict__ out_n, int N) {
    __shared__ float a_lds[4][64];
    __shared__ int   s_lds3[4][64];
    const int t = threadIdx.x, wid = t >> 6, lane = t & 63;
    const int col = lane & 31, half = lane >> 5;
    const int i = blockIdx.x * 4 + wid;
    if (i >= N) return;
    const int start = ptr[i], end = ptr[i + 1];
    const int deg = end - start;
    const float aldv = ald[i];
    const float e0 = lrelu(als[i] + aldv);
    float acc = 0.f;

    if (deg <= 64) {
        // ---- single-pass fast path ----
        int sreg = 0; float ev = -1e30f;
        if (lane < deg) { sreg = csr[start + lane]; ev = lrelu(als[sreg] + aldv); }
        float mx = fmaxf(e0, ev);
        #pragma unroll
        for (int off = 32; off >= 1; off >>= 1) mx = fmaxf(mx, __shfl_xor(mx, off));
        float ex = (lane < deg) ? expf(ev - mx) : 0.f;
        float sm = ex + ((lane == 0) ? expf(e0 - mx) : 0.f);
        #pragma unroll
        for (int off = 32; off >= 1; off >>= 1) sm += __shfl_xor(sm, off);
        const float inv = 1.f / (sm + 1e-16f);
        a_lds[wid][lane] = ex * inv;
        s_lds3[wid][lane] = sreg;
        if (half == 0) acc = expf(e0 - mx) * inv * h3[(size_t)i * 32 + col];

        // halves own alternate edges; 4 loads in flight per half (8/wave)
        int k = half;
        for (; k + 6 < deg; k += 8) {
            const int s0 = s_lds3[wid][k],     s1 = s_lds3[wid][k + 2];
            const int s2 = s_lds3[wid][k + 4], s3 = s_lds3[wid][k + 6];
            const float a0 = a_lds[wid][k],     a1 = a_lds[wid][k + 2];
            const float a2 = a_lds[wid][k + 4], a3 = a_lds[wid][k + 6];
            const float v0 = h3[(size_t)s0 * 32 + col];
            const float v1 = h3[(size_t)s1 * 32 + col];
            const float v2 = h3[(size_t)s2 * 32 + col];
            const float v3 = h3[(size_t)s3 * 32 + col];
            acc = fmaf(a0, v0, acc); acc = fmaf(a1, v1, acc);
            acc = fmaf(a2, v2, acc); acc = fmaf(a3, v3, acc);
        }
        for (; k < deg; k += 2)
            acc = fmaf(a_lds[wid][k], h3[(size_t)s_lds3[wid][k] * 32 + col], acc);
    } else {
        // ---- streaming fallback (rare) ----
        float mx = e0;
        for (int j = start + lane; j < end; j += 64)
            mx = fmaxf(mx, lrelu(als[csr[j]] + aldv));
        #pragma unroll
        for (int off = 32; off >= 1; off >>= 1) mx = fmaxf(mx, __shfl_xor(mx, off));
        float sm = (lane == 0) ? expf(e0 - mx) : 0.f;
        for (int j = start + lane; j < end; j += 64)
            sm += expf(lrelu(als[csr[j]] + aldv) - mx);
        #pragma unroll
        for (int off = 32; off >= 1; off >>= 1) sm += __shfl_xor(sm, off);
        const float inv = 1.f / (sm + 1e-16f);
        if (half == 0) acc = expf(e0 - mx) * inv * h3[(size_t)i * 32 + col];
        for (int base = start; base < end; base += 64) {
            const int n64 = min(64, end - base);
            const int j = base + lane;
            int sreg = 0; float av = 0.f;
            if (j < end) {
                sreg = csr[j];
                av = expf(lrelu(als[sreg] + aldv) - mx) * inv;
            }
            a_lds[wid][lane] = av;
            s_lds3[wid][lane] = sreg;
            for (int k = half; k < n64; k += 2)
                acc = fmaf(a_lds[wid][k], h3[(size_t)s_lds3[wid][k] * 32 + col], acc);
        }
    }

    acc += __shfl_down(acc, 32);
    if (half == 0)
        out_n[(size_t)i * 32 + col] = acc + bias[col];   // no ReLU on layer 3
}

// ---------------- deterministic segmented mean pool (batch sorted) ----------------
__global__ __launch_bounds__(256) void pool_kernel(const float* __restrict__ out_n,
        const int* __restrict__ gstart, float* __restrict__ out, int G) {
    const int t = threadIdx.x, wid = t >> 6, lane = t & 63;
    const int col = lane & 31, half = lane >> 5;
    const int g = blockIdx.x * 4 + wid;
    if (g >= G) return;
    const int s = gstart[g], e = gstart[g + 1];
    float acc = 0.f;
    int r = s + half;
    for (; r + 6 < e; r += 8) {
        acc += out_n[(size_t)r * 32 + col];
        acc += out_n[(size_t)(r + 2) * 32 + col];
        acc += out_n[(size_t)(r + 4) * 32 + col];
        acc += out_n[(size_t)(r + 6) * 32 + col];
    }
    for (; r < e; r += 2) acc += out_n[(size_t)r * 32 + col];
    acc += __shfl_down(acc, 32);
    if (half == 0)
        out[g * 32 + col] = acc / fmaxf((float)(e - s), 1.f);
}

extern "C" void kernel_launch(void* const* d_in, const int* in_sizes, int n_in,
                              void* d_out, int out_size, void* d_ws, size_t ws_size,
                              hipStream_t stream) {
    const int N = 50000, E = 800000, G = 512;
    const float* x    = (const float*)d_in[0];
    const int*   ei   = (const int*)d_in[1];
    const int*   batch= (const int*)d_in[2];
    const float* W1   = (const float*)d_in[3];
    const float* as1  = (const float*)d_in[4];
    const float* ad1  = (const float*)d_in[5];
    const float* b1   = (const float*)d_in[6];
    const float* W2   = (const float*)d_in[7];
    const float* as2  = (const float*)d_in[8];
    const float* ad2  = (const float*)d_in[9];
    const float* b2   = (const float*)d_in[10];
    const float* W3   = (const float*)d_in[11];
    const float* as3  = (const float*)d_in[12];
    const float* ad3  = (const float*)d_in[13];
    const float* b3   = (const float*)d_in[14];
    const int* esrc = ei;
    const int* edst = ei + E;

    char* base = (char*)d_ws; size_t off = 0;
    auto alloc = [&](size_t bytes) -> void* {
        void* p = base + off; off = (off + bytes + 255) & ~(size_t)255; return p;
    };
    u16*   hbuf = (u16*)  alloc((size_t)N * 256 * 2);   // GEMM out / messages (bf16)
    u16*   act  = (u16*)  alloc((size_t)N * 256 * 2);   // bf16 activations
    float* h3   = (float*)alloc((size_t)N * 32 * 4);    // layer-3 pre-agg (fp32)
    float* als  = (float*)alloc((size_t)N * 4 * 4);
    float* ald  = (float*)alloc((size_t)N * 4 * 4);
    int*   deg  = (int*)  alloc((size_t)N * 4);
    int*   ptr  = (int*)  alloc((size_t)(N + 1) * 4);
    int*   cur  = (int*)  alloc((size_t)N * 4);
    int*   csr  = (int*)  alloc((size_t)E * 4);
    u16*   Wt   = (u16*)  alloc((size_t)256 * 800 * 2);
    int*   bsum = (int*)  alloc((size_t)64 * 4);
    float* out_n= (float*)alloc((size_t)N * 32 * 4);    // per-node layer-3 output
    int*   gstart=(int*)  alloc((size_t)(G + 1) * 4);
    float* xtail= (float*)alloc((size_t)N * 32 * 4);    // padded x[:,768:800] (6.4MB)

    hipMemsetAsync(deg, 0, (size_t)N * 4, stream);

    // CSR over dst (reused by all 3 layers; self-loop handled via eself term)
    const int nb = (N + 1023) / 1024;
    deg_kernel<<<(E + 255) / 256, 256, 0, stream>>>(edst, deg, E);
    scan_local<<<nb, 1024, 0, stream>>>(deg, ptr, bsum, N);
    scan_carry<<<1, 64, 0, stream>>>(bsum, nb);
    scan_final<<<nb, 1024, 0, stream>>>(deg, ptr, cur, bsum, N);
    fill_kernel<<<(E + 255) / 256, 256, 0, stream>>>(esrc, edst, cur, csr, E);
    bounds_kernel<<<(N + 256) / 256, 256, 0, stream>>>(batch, gstart, N, G);

    dim3 gemmGrid(2, (N + 127) / 128);               // col-block fast axis: L2 A-sharing
    const int aggGrid = (N + 3) / 4;
    // ---- layer 1 (fp32 x via triple-buffered counted-vmcnt glds pipeline) ----
    transpose_w<<<(256 * 800 + 255) / 256, 256, 0, stream>>>(W1, Wt, 775, 256, 800);
    tail_kernel<<<(N * 32 + 255) / 256, 256, 0, stream>>>(x, xtail, N);
    gemm_glds_f32<<<gemmGrid, 256, 0, stream>>>(x, 775, N, xtail, Wt, 800, hbuf, 256);
    al_kernel<<<(N + 7) / 8, 256, 0, stream>>>(hbuf, as1, ad1, als, ald, N);
    agg_kernel<<<aggGrid, 256, 0, stream>>>(hbuf, als, ald, ptr, csr, b1, act, N);
    // ---- layer 2 ----
    transpose_w<<<(256 * 256 + 255) / 256, 256, 0, stream>>>(W2, Wt, 256, 256, 256);
    gemm_glds<<<gemmGrid, 256, 0, stream>>>(act, 256, N, 256, Wt, 256, hbuf, 256);
    al_kernel<<<(N + 7) / 8, 256, 0, stream>>>(hbuf, as2, ad2, als, ald, N);
    agg_kernel<<<aggGrid, 256, 0, stream>>>(hbuf, als, ald, ptr, csr, b2, act, N);
    // ---- layer 3 ----
    transpose_w<<<(32 * 256 + 255) / 256, 256, 0, stream>>>(W3, Wt, 256, 32, 256);
    gemm32<<<(N + 127) / 128, 256, 0, stream>>>(act, 256, N, 256, Wt, 256, h3);
    al3_kernel<<<(N + 7) / 8, 256, 0, stream>>>(h3, as3, ad3, als, ald, N);
    agg3_kernel<<<aggGrid, 256, 0, stream>>>(h3, als, ald, ptr, csr, b3, out_n, N);
    pool_kernel<<<(G + 3) / 4, 256, 0, stream>>>(out_n, gstart, (float*)d_out, G);
}

// Round 13
// 609.181 us; speedup vs baseline: 1.0134x; 1.0134x over previous
//
#include <hip/hip_runtime.h>
#include <hip/hip_bf16.h>

typedef unsigned short u16;
typedef __attribute__((ext_vector_type(4))) unsigned short u16x4;
typedef __attribute__((ext_vector_type(8))) unsigned short u16x8;
typedef __attribute__((ext_vector_type(8))) short bf16x8;
typedef __attribute__((ext_vector_type(4))) float f32x4;

__device__ __forceinline__ u16 f2bs(float f) {
    union { float f; unsigned int u; } x; x.f = f;
    unsigned int r = x.u + 0x7FFFu + ((x.u >> 16) & 1u);   // RNE
    return (u16)(r >> 16);
}
__device__ __forceinline__ float bs2f(u16 u) {
    union { unsigned int u; float f; } x; x.u = ((unsigned int)u) << 16; return x.f;
}
__device__ __forceinline__ float lrelu(float e) { return e >= 0.f ? e : 0.2f * e; }

// packed f32->bf16 RNE, 2 elements per VALU op (gfx950). Low half = src0.
__device__ __forceinline__ unsigned cvtpk(float lo, float hi) {
    unsigned r;
    asm("v_cvt_pk_bf16_f32 %0, %1, %2" : "=v"(r) : "v"(lo), "v"(hi));
    return r;
}

// async global->LDS, 16B/lane; lds dest is wave-uniform base (HW adds lane*16)
__device__ __forceinline__ void glds16(const void* g, void* l) {
    __builtin_amdgcn_global_load_lds(
        (const __attribute__((address_space(1))) unsigned int*)g,
        (__attribute__((address_space(3))) unsigned int*)l, 16, 0, 0);
}

// bijective XCD chunk swizzle (m204): consecutive logical tiles stay on one XCD
__device__ __forceinline__ int xcd_swz(int bid, int nwg) {
    int q = nwg >> 3, r = nwg & 7;
    int xcd = bid & 7, pos = bid >> 3;
    int base = (xcd < r) ? xcd * (q + 1) : r * (q + 1) + (xcd - r) * q;
    return base + pos;
}

// ---------------- CSR build ----------------
__global__ void deg_kernel(const int* __restrict__ dst, int* __restrict__ deg, int E) {
    int i = blockIdx.x * 256 + threadIdx.x;
    if (i < E) atomicAdd(&deg[dst[i]], 1);
}

// hierarchical scan: local (1024/block) -> carry scan -> fixup
__global__ __launch_bounds__(1024) void scan_local(const int* __restrict__ deg,
        int* __restrict__ ptr, int* __restrict__ bsum, int N) {
    __shared__ int wsum[16];
    const int t = threadIdx.x, i = blockIdx.x * 1024 + t;
    const int lane = t & 63, w = t >> 6;
    int v = (i < N) ? deg[i] : 0;
    int x = v;
    #pragma unroll
    for (int off = 1; off < 64; off <<= 1) { int y = __shfl_up(x, off); if (lane >= off) x += y; }
    if (lane == 63) wsum[w] = x;
    __syncthreads();
    if (w == 0) {
        int s = (lane < 16) ? wsum[lane] : 0;
        #pragma unroll
        for (int off = 1; off < 16; off <<= 1) { int y = __shfl_up(s, off); if (lane >= off) s += y; }
        if (lane < 16) wsum[lane] = s;
    }
    __syncthreads();
    int incl = x + (w > 0 ? wsum[w - 1] : 0);
    if (i < N) ptr[i + 1] = incl;            // local inclusive; fixed by scan_final
    if (t == 0) bsum[blockIdx.x] = wsum[15];
}

__global__ __launch_bounds__(64) void scan_carry(int* __restrict__ bsum, int nb) {
    int t = threadIdx.x;
    int v = (t < nb) ? bsum[t] : 0;
    int x = v;
    #pragma unroll
    for (int off = 1; off < 64; off <<= 1) { int y = __shfl_up(x, off); if (t >= off) x += y; }
    if (t < nb) bsum[t] = x - v;             // exclusive
}

__global__ __launch_bounds__(1024) void scan_final(const int* __restrict__ deg,
        int* __restrict__ ptr, int* __restrict__ cur, const int* __restrict__ bsum, int N) {
    int i = blockIdx.x * 1024 + threadIdx.x;
    if (i == 0) ptr[0] = 0;
    if (i < N) {
        int p = ptr[i + 1] + bsum[blockIdx.x];
        ptr[i + 1] = p;
        cur[i] = p - deg[i];
    }
}

__global__ void fill_kernel(const int* __restrict__ src, const int* __restrict__ dst,
        int* __restrict__ cur, int* __restrict__ csr, int E) {
    int i = blockIdx.x * 256 + threadIdx.x;
    if (i < E) { int p = atomicAdd(&cur[dst[i]], 1); csr[p] = src[i]; }
}

// ---------------- graph boundary index (batch is sorted) ----------------
__global__ void bounds_kernel(const int* __restrict__ batch, int* __restrict__ gstart,
        int N, int G) {
    int i = blockIdx.x * 256 + threadIdx.x;
    if (i > N) return;
    if (i == 0) {
        int b0 = batch[0];
        for (int g = 0; g <= b0; g++) gstart[g] = 0;
    } else if (i == N) {
        int bl = batch[N - 1];
        for (int g = bl + 1; g <= G; g++) gstart[g] = N;
    } else {
        int b = batch[i], bp = batch[i - 1];
        for (int g = bp + 1; g <= b; g++) gstart[g] = i;
    }
}

// ---------------- weight transpose: fp32 W[K][Nn] -> bf16 Wt[Nn][KT] (zero-pad k>=K) ----
__global__ void transpose_w(const float* __restrict__ W, u16* __restrict__ Wt,
        int K, int Nn, int KT) {
    int idx = blockIdx.x * 256 + threadIdx.x;
    if (idx >= Nn * KT) return;
    int n = idx / KT, k = idx - n * KT;
    Wt[(size_t)n * KT + k] = (k < K) ? f2bs(W[(size_t)k * Nn + n]) : (u16)0;
}

// ---------------- x tail pack: xtail[n][j] = x[n][768+j] (j<7), else 0 --------------
__global__ __launch_bounds__(256) void tail_kernel(const float* __restrict__ x,
        float* __restrict__ xtail, int N) {
    int idx = blockIdx.x * 256 + threadIdx.x;
    if (idx >= N * 32) return;
    int n = idx >> 5, j = idx & 31;
    xtail[idx] = (768 + j < 775) ? x[(size_t)n * 775 + 768 + j] : 0.f;
}

// ---------------- layer-1 GEMM: C[M,256] bf16 = fp32 A[M,775] @ Wt^T ----------------
// Round-11 triple-buffered counted-vmcnt pipeline + (a) 1D grid with bijective XCD
// swizzle (col-block pairs sharing an A panel land on one XCD -> partner A fetch is
// an L2 hit), (b) s_setprio around the MFMA cluster (T5; pipeline gives phase-split),
// (c) FUSED attention scalars: each wave's 64 cols = one head, so al_s/al_d reduce
// in-wave (width-16 shfl) on the f2bs'd h values (bit-identical to old al_kernel).
__global__ __launch_bounds__(256) void gemm_glds_f32(
        const float* __restrict__ A, int lda, int M,
        const float* __restrict__ Atail,
        const u16* __restrict__ B, int ldb,
        u16* __restrict__ C, int ldc,
        const float* __restrict__ a_s, const float* __restrict__ a_d,
        float* __restrict__ als, float* __restrict__ ald) {
    __shared__ float Aldsf[3][128][32];
    __shared__ u16   Blds[3][128][32];
    const int t = threadIdx.x;
    const int id = xcd_swz(blockIdx.x, gridDim.x);
    const int cx = id & 1;
    const int col0 = cx * 128;
    const int row0 = (id >> 1) * 128;
    const int wid = t >> 6, lane = t & 63;
    const int wm = wid >> 1, wn = wid & 1;
    const int quad = lane >> 4, l16 = lane & 15;

    f32x4 acc[4][4];
    f32x4 z = {0.f, 0.f, 0.f, 0.f};
    #pragma unroll
    for (int i = 0; i < 4; i++)
        #pragma unroll
        for (int j = 0; j < 4; j++) acc[i][j] = z;

    const int trb = wid * 32 + (lane >> 2);   // B staging row base
    const int arl = lane >> 3;                // A staging: row within 8-row chunk
    const int asg = lane & 7;                 // A staging: 16B group

    auto stage = [&](int buf, int kt) {       // 6 glds16 per lane per call
        const int k0 = kt << 5;
        #pragma unroll
        for (int c = 0; c < 2; c++) {
            const int tr = trb + c * 16;
            const int ks = ((lane & 3) ^ ((tr >> 1) & 3)) * 8;
            glds16(B + (size_t)(col0 + tr) * ldb + k0 + ks, &Blds[buf][wid * 32 + c * 16][0]);
        }
        #pragma unroll
        for (int c = 0; c < 4; c++) {
            const int rt = wid * 32 + c * 8 + arl;          // tile row
            int gra = row0 + rt; if (gra > M - 1) gra = M - 1;
            const int sg = (asg ^ ((rt & 3) << 1)) * 4;     // source float offset
            const float* src = (kt < 24) ? (A + (size_t)gra * lda + k0 + sg)
                                         : (Atail + (size_t)gra * 32 + sg);
            glds16(src, &Aldsf[buf][wid * 32 + c * 8][0]);
        }
    };
    auto compute = [&](int buf) {
        bf16x8 af[4], bfr[4];
        #pragma unroll
        for (int it = 0; it < 4; it++) {
            const int r = wm * 64 + it * 16 + l16;
            const int go = ((2 * quad) ^ ((r & 3) << 1)) * 4;  // float offset of k-chunk 2q
            const f32x4 lo = *(const f32x4*)&Aldsf[buf][r][go];
            const f32x4 hi = *(const f32x4*)&Aldsf[buf][r][go + 4];
            union { unsigned u[4]; bf16x8 v; } uu;
            uu.u[0] = cvtpk(lo[0], lo[1]);
            uu.u[1] = cvtpk(lo[2], lo[3]);
            uu.u[2] = cvtpk(hi[0], hi[1]);
            uu.u[3] = cvtpk(hi[2], hi[3]);
            af[it] = uu.v;
        }
        #pragma unroll
        for (int jt = 0; jt < 4; jt++) {
            const int r = wn * 64 + jt * 16 + l16;
            bfr[jt] = *(const bf16x8*)&Blds[buf][r][(quad ^ ((r >> 1) & 3)) * 8];
        }
        __builtin_amdgcn_s_setprio(1);
        #pragma unroll
        for (int it = 0; it < 4; it++)
            #pragma unroll
            for (int jt = 0; jt < 4; jt++)
                acc[it][jt] = __builtin_amdgcn_mfma_f32_16x16x32_bf16(af[it], bfr[jt], acc[it][jt], 0, 0, 0);
        __builtin_amdgcn_s_setprio(0);
    };

    const int kTiles = 25;                    // 24 full from A + 1 from Atail
    stage(0, 0);
    stage(1, 1);
    for (int kt = 0; kt < kTiles - 1; ++kt) {
        asm volatile("s_waitcnt vmcnt(6)" ::: "memory");   // tile kt ready (mine)
        __builtin_amdgcn_sched_barrier(0);
        __builtin_amdgcn_s_barrier();                      // everyone ready + compute(kt-1) done
        __builtin_amdgcn_sched_barrier(0);
        if (kt + 2 < kTiles) stage((kt + 2) % 3, kt + 2);  // overwrites buf read at kt-1: safe
        compute(kt % 3);
    }
    asm volatile("s_waitcnt vmcnt(0)" ::: "memory");       // final tile: drain
    __builtin_amdgcn_sched_barrier(0);
    __builtin_amdgcn_s_barrier();
    __builtin_amdgcn_sched_barrier(0);
    compute((kTiles - 1) % 3);

    // ---- epilogue: C-store + fused per-head attention scalars ----
    const int hd = cx * 2 + wn;               // this wave's head (0..3)
    float asv[4], adv[4];
    #pragma unroll
    for (int jt = 0; jt < 4; jt++) {
        asv[jt] = a_s[hd * 64 + jt * 16 + l16];
        adv[jt] = a_d[hd * 64 + jt * 16 + l16];
    }
    #pragma unroll
    for (int it = 0; it < 4; it++) {
        int gr0 = row0 + wm * 64 + it * 16 + quad * 4;
        #pragma unroll
        for (int r = 0; r < 4; r++) {
            int gr = gr0 + r;
            u16 ov[4];
            float ps = 0.f, pd = 0.f;
            #pragma unroll
            for (int jt = 0; jt < 4; jt++) {
                u16 o = f2bs(acc[it][jt][r]);
                ov[jt] = o;
                float hv = bs2f(o);
                ps = fmaf(hv, asv[jt], ps);
                pd = fmaf(hv, adv[jt], pd);
            }
            if (gr < M) {
                #pragma unroll
                for (int jt = 0; jt < 4; jt++)
                    C[(size_t)gr * ldc + col0 + wn * 64 + jt * 16 + l16] = ov[jt];
            }
            #pragma unroll
            for (int off = 8; off >= 1; off >>= 1) {
                ps += __shfl_xor(ps, off, 16);
                pd += __shfl_xor(pd, off, 16);
            }
            if (l16 == 0 && gr < M) {
                als[gr * 4 + hd] = ps;
                ald[gr * 4 + hd] = pd;
            }
        }
    }
}

// ---------------- GEMM: C[M,256] bf16 = A[M,K]bf16 @ Wt^T (layer 2) ----------------
// Same pipeline/swizzle/setprio/fused-al, bf16 A (4 glds/stage -> vmcnt(4)).
__global__ __launch_bounds__(256) void gemm_glds(
        const u16* __restrict__ A, int lda, int M, int K,
        const u16* __restrict__ B, int ldb,
        u16* __restrict__ C, int ldc,
        const float* __restrict__ a_s, const float* __restrict__ a_d,
        float* __restrict__ als, float* __restrict__ ald) {
    __shared__ u16 Alds[3][128][32];
    __shared__ u16 Blds[3][128][32];
    const int t = threadIdx.x;
    const int id = xcd_swz(blockIdx.x, gridDim.x);
    const int cx = id & 1;
    const int col0 = cx * 128;
    const int row0 = (id >> 1) * 128;
    const int wid = t >> 6, lane = t & 63;
    const int wm = wid >> 1, wn = wid & 1;
    const int quad = lane >> 4, l16 = lane & 15;

    f32x4 acc[4][4];
    f32x4 z = {0.f, 0.f, 0.f, 0.f};
    #pragma unroll
    for (int i = 0; i < 4; i++)
        #pragma unroll
        for (int j = 0; j < 4; j++) acc[i][j] = z;

    const int trb = wid * 32 + (lane >> 2);

    auto stage = [&](int buf, int kt) {       // 4 glds16 per lane per call
        const int k0 = kt << 5;
        #pragma unroll
        for (int c = 0; c < 2; c++) {
            const int tr = trb + c * 16;
            const int ks = ((lane & 3) ^ ((tr >> 1) & 3)) * 8;   // swizzled source chunk
            int gra = row0 + tr; if (gra > M - 1) gra = M - 1;   // clamp: junk rows unused
            glds16(A + (size_t)gra * lda + k0 + ks, &Alds[buf][wid * 32 + c * 16][0]);
            glds16(B + (size_t)(col0 + tr) * ldb + k0 + ks, &Blds[buf][wid * 32 + c * 16][0]);
        }
    };
    auto compute = [&](int buf) {
        bf16x8 af[4], bfr[4];
        #pragma unroll
        for (int it = 0; it < 4; it++) {
            const int r = wm * 64 + it * 16 + l16;
            af[it] = *(const bf16x8*)&Alds[buf][r][(quad ^ ((r >> 1) & 3)) * 8];
        }
        #pragma unroll
        for (int jt = 0; jt < 4; jt++) {
            const int r = wn * 64 + jt * 16 + l16;
            bfr[jt] = *(const bf16x8*)&Blds[buf][r][(quad ^ ((r >> 1) & 3)) * 8];
        }
        __builtin_amdgcn_s_setprio(1);
        #pragma unroll
        for (int it = 0; it < 4; it++)
            #pragma unroll
            for (int jt = 0; jt < 4; jt++)
                acc[it][jt] = __builtin_amdgcn_mfma_f32_16x16x32_bf16(af[it], bfr[jt], acc[it][jt], 0, 0, 0);
        __builtin_amdgcn_s_setprio(0);
    };

    const int kTiles = K >> 5;
    stage(0, 0);
    stage(1, 1);
    for (int kt = 0; kt < kTiles - 1; ++kt) {
        asm volatile("s_waitcnt vmcnt(4)" ::: "memory");
        __builtin_amdgcn_sched_barrier(0);
        __builtin_amdgcn_s_barrier();
        __builtin_amdgcn_sched_barrier(0);
        if (kt + 2 < kTiles) stage((kt + 2) % 3, kt + 2);
        compute(kt % 3);
    }
    asm volatile("s_waitcnt vmcnt(0)" ::: "memory");
    __builtin_amdgcn_sched_barrier(0);
    __builtin_amdgcn_s_barrier();
    __builtin_amdgcn_sched_barrier(0);
    compute((kTiles - 1) % 3);

    // ---- epilogue: C-store + fused per-head attention scalars ----
    const int hd = cx * 2 + wn;
    float asv[4], adv[4];
    #pragma unroll
    for (int jt = 0; jt < 4; jt++) {
        asv[jt] = a_s[hd * 64 + jt * 16 + l16];
        adv[jt] = a_d[hd * 64 + jt * 16 + l16];
    }
    #pragma unroll
    for (int it = 0; it < 4; it++) {
        int gr0 = row0 + wm * 64 + it * 16 + quad * 4;
        #pragma unroll
        for (int r = 0; r < 4; r++) {
            int gr = gr0 + r;
            u16 ov[4];
            float ps = 0.f, pd = 0.f;
            #pragma unroll
            for (int jt = 0; jt < 4; jt++) {
                u16 o = f2bs(acc[it][jt][r]);
                ov[jt] = o;
                float hv = bs2f(o);
                ps = fmaf(hv, asv[jt], ps);
                pd = fmaf(hv, adv[jt], pd);
            }
            if (gr < M) {
                #pragma unroll
                for (int jt = 0; jt < 4; jt++)
                    C[(size_t)gr * ldc + col0 + wn * 64 + jt * 16 + l16] = ov[jt];
            }
            #pragma unroll
            for (int off = 8; off >= 1; off >>= 1) {
                ps += __shfl_xor(ps, off, 16);
                pd += __shfl_xor(pd, off, 16);
            }
            if (l16 == 0 && gr < M) {
                als[gr * 4 + hd] = ps;
                ald[gr * 4 + hd] = pd;
            }
        }
    }
}

// GEMM for layer3: C[M,32] fp32 = A[M,256]bf16 @ Wt3^T (h3 stays fp32 — tiny)
__global__ __launch_bounds__(256) void gemm32(
        const u16* __restrict__ A, int lda, int M, int K,
        const u16* __restrict__ B, int ldb, float* __restrict__ C) {
    __shared__ u16 Alds[128][40];
    __shared__ u16 Blds[32][40];
    const int t = threadIdx.x;
    const int row0 = blockIdx.x * 128;
    const int wid = t >> 6, lane = t & 63;
    const int quad = lane >> 4, l16 = lane & 15;
    f32x4 acc[2][2];
    f32x4 z = {0.f, 0.f, 0.f, 0.f};
    acc[0][0] = z; acc[0][1] = z; acc[1][0] = z; acc[1][1] = z;
    const int kTiles = K >> 5;
    for (int kt = 0; kt < kTiles; ++kt) {
        const int k0 = kt << 5;
        #pragma unroll
        for (int c = 0; c < 2; c++) {
            int ch = t + c * 256;
            int r = ch >> 2, cp = (ch & 3) * 8;
            int gr = row0 + r;
            u16x8 v = {0,0,0,0,0,0,0,0};
            if (gr < M) v = *(const u16x8*)(A + (size_t)gr * lda + k0 + cp);
            *(u16x8*)&Alds[r][cp] = v;
        }
        if (t < 128) {
            int r = t >> 2, cp = (t & 3) * 8;
            *(u16x8*)&Blds[r][cp] = *(const u16x8*)(B + (size_t)r * ldb + k0 + cp);
        }
        __syncthreads();
        bf16x8 af[2], bfr[2];
        #pragma unroll
        for (int it = 0; it < 2; it++) af[it] = *(const bf16x8*)&Alds[wid * 32 + it * 16 + l16][quad * 8];
        #pragma unroll
        for (int jt = 0; jt < 2; jt++) bfr[jt] = *(const bf16x8*)&Blds[jt * 16 + l16][quad * 8];
        #pragma unroll
        for (int it = 0; it < 2; it++)
            #pragma unroll
            for (int jt = 0; jt < 2; jt++)
                acc[it][jt] = __builtin_amdgcn_mfma_f32_16x16x32_bf16(af[it], bfr[jt], acc[it][jt], 0, 0, 0);
        __syncthreads();
    }
    #pragma unroll
    for (int it = 0; it < 2; it++) {
        int gr0 = row0 + wid * 32 + it * 16 + quad * 4;
        #pragma unroll
        for (int jt = 0; jt < 2; jt++) {
            int gc = jt * 16 + l16;
            #pragma unroll
            for (int r = 0; r < 4; r++) {
                int gr = gr0 + r;
                if (gr < M) C[(size_t)gr * 32 + gc] = acc[it][jt][r];
            }
        }
    }
}

__global__ __launch_bounds__(256) void al3_kernel(const float* __restrict__ h3,
        const float* __restrict__ a_s, const float* __restrict__ a_d,
        float* __restrict__ als, float* __restrict__ ald, int N) {
    int t = threadIdx.x, wid = t >> 6, lane = t & 63;
    int c = lane & 31, half = lane >> 5;
    float as = a_s[c], ad = a_d[c];
    int n = blockIdx.x * 8 + wid * 2 + half;
    if (n >= N) return;
    float hv = h3[(size_t)n * 32 + c];
    float ps = hv * as, pd = hv * ad;
    for (int off = 16; off >= 1; off >>= 1) { ps += __shfl_down(ps, off, 32); pd += __shfl_down(pd, off, 32); }
    if (c == 0) { als[n] = ps; ald[n] = pd; }
}

// ---------------- softmax-aggregation (H=4, C=64): one wave per node, bf16 h ----------------
// Single pass (deg<=64): e in registers, (s,alpha) staged in LDS once.
// Gather: 16B/lane, 32 lanes per neighbor row; halves own alternate edges ->
// 8 independent loads in flight per wave. Streaming fallback for deg>64.
__global__ __launch_bounds__(256) void agg_kernel(const u16* __restrict__ hbuf,
        const float* __restrict__ als, const float* __restrict__ ald,
        const int* __restrict__ ptr, const int* __restrict__ csr,
        const float* __restrict__ bias, u16* __restrict__ act, int N) {
    __shared__ float al_lds[4][64][4];
    __shared__ int   s_lds[4][64];
    const int t = threadIdx.x, wid = t >> 6, lane = t & 63;
    const int i = blockIdx.x * 4 + wid;
    if (i >= N) return;
    const int start = ptr[i], end = ptr[i + 1];
    const int deg = end - start;
    const int col8 = lane & 31;          // which 8-feature chunk of the 256-wide row
    const int half = lane >> 5;
    const int head8 = col8 >> 3;         // head owning this lane's 8 features

    const f32x4 aldv = *(const f32x4*)&ald[(size_t)i * 4];
    const f32x4 alsv = *(const f32x4*)&als[(size_t)i * 4];
    f32x4 eself;
    #pragma unroll
    for (int hh = 0; hh < 4; hh++) eself[hh] = lrelu(alsv[hh] + aldv[hh]);

    float acc[8];
    f32x4 mx, inv;

    if (deg <= 64) {
        // ---- single-pass softmax ----
        int sreg = 0;
        f32x4 ev;
        #pragma unroll
        for (int hh = 0; hh < 4; hh++) ev[hh] = -1e30f;
        if (lane < deg) {
            sreg = csr[start + lane];
            const f32x4 a = *(const f32x4*)&als[(size_t)sreg * 4];
            #pragma unroll
            for (int hh = 0; hh < 4; hh++) ev[hh] = lrelu(a[hh] + aldv[hh]);
        }
        #pragma unroll
        for (int hh = 0; hh < 4; hh++) mx[hh] = fmaxf(eself[hh], ev[hh]);
        #pragma unroll
        for (int off = 32; off >= 1; off >>= 1) {
            #pragma unroll
            for (int hh = 0; hh < 4; hh++) mx[hh] = fmaxf(mx[hh], __shfl_xor(mx[hh], off));
        }
        f32x4 sm, av;
        #pragma unroll
        for (int hh = 0; hh < 4; hh++) {
            av[hh] = (lane < deg) ? expf(ev[hh] - mx[hh]) : 0.f;
            sm[hh] = av[hh] + ((lane == 0) ? expf(eself[hh] - mx[hh]) : 0.f);
        }
        #pragma unroll
        for (int off = 32; off >= 1; off >>= 1) {
            #pragma unroll
            for (int hh = 0; hh < 4; hh++) sm[hh] += __shfl_xor(sm[hh], off);
        }
        #pragma unroll
        for (int hh = 0; hh < 4; hh++) inv[hh] = 1.f / (sm[hh] + 1e-16f);
        #pragma unroll
        for (int hh = 0; hh < 4; hh++) av[hh] *= inv[hh];
        *(f32x4*)&al_lds[wid][lane][0] = av;
        s_lds[wid][lane] = sreg;

        // ---- gather: 16B/lane, halves interleave edges ----
        const u16x8 hrs = *(const u16x8*)&hbuf[(size_t)i * 256 + col8 * 8];
        const float aself = expf(eself[head8] - mx[head8]) * inv[head8];
        #pragma unroll
        for (int c = 0; c < 8; c++) acc[c] = (half == 0) ? aself * bs2f(hrs[c]) : 0.f;

        int k = half;
        for (; k + 6 < deg; k += 8) {
            const int s0 = s_lds[wid][k],     s1 = s_lds[wid][k + 2];
            const int s2 = s_lds[wid][k + 4], s3 = s_lds[wid][k + 6];
            const float a0 = al_lds[wid][k][head8],     a1 = al_lds[wid][k + 2][head8];
            const float a2 = al_lds[wid][k + 4][head8], a3 = al_lds[wid][k + 6][head8];
            const u16x8 h0 = *(const u16x8*)&hbuf[(size_t)s0 * 256 + col8 * 8];
            const u16x8 h1 = *(const u16x8*)&hbuf[(size_t)s1 * 256 + col8 * 8];
            const u16x8 h2 = *(const u16x8*)&hbuf[(size_t)s2 * 256 + col8 * 8];
            const u16x8 h3v = *(const u16x8*)&hbuf[(size_t)s3 * 256 + col8 * 8];
            #pragma unroll
            for (int c = 0; c < 8; c++) {
                acc[c] = fmaf(a0, bs2f(h0[c]), acc[c]);
                acc[c] = fmaf(a1, bs2f(h1[c]), acc[c]);
                acc[c] = fmaf(a2, bs2f(h2[c]), acc[c]);
                acc[c] = fmaf(a3, bs2f(h3v[c]), acc[c]);
            }
        }
        for (; k < deg; k += 2) {
            const int s = s_lds[wid][k];
            const float a = al_lds[wid][k][head8];
            const u16x8 hr = *(const u16x8*)&hbuf[(size_t)s * 256 + col8 * 8];
            #pragma unroll
            for (int c = 0; c < 8; c++) acc[c] = fmaf(a, bs2f(hr[c]), acc[c]);
        }
    } else {
        // ---- streaming fallback (rare) ----
        mx = eself;
        for (int j = start + lane; j < end; j += 64) {
            int s = csr[j];
            const f32x4 a = *(const f32x4*)&als[(size_t)s * 4];
            #pragma unroll
            for (int hh = 0; hh < 4; hh++) mx[hh] = fmaxf(mx[hh], lrelu(a[hh] + aldv[hh]));
        }
        #pragma unroll
        for (int off = 32; off >= 1; off >>= 1) {
            #pragma unroll
            for (int hh = 0; hh < 4; hh++) mx[hh] = fmaxf(mx[hh], __shfl_xor(mx[hh], off));
        }
        f32x4 sm;
        #pragma unroll
        for (int hh = 0; hh < 4; hh++) sm[hh] = (lane == 0) ? expf(eself[hh] - mx[hh]) : 0.f;
        for (int j = start + lane; j < end; j += 64) {
            int s = csr[j];
            const f32x4 a = *(const f32x4*)&als[(size_t)s * 4];
            #pragma unroll
            for (int hh = 0; hh < 4; hh++) sm[hh] += expf(lrelu(a[hh] + aldv[hh]) - mx[hh]);
        }
        #pragma unroll
        for (int off = 32; off >= 1; off >>= 1) {
            #pragma unroll
            for (int hh = 0; hh < 4; hh++) sm[hh] += __shfl_xor(sm[hh], off);
        }
        #pragma unroll
        for (int hh = 0; hh < 4; hh++) inv[hh] = 1.f / (sm[hh] + 1e-16f);

        const u16x8 hrs = *(const u16x8*)&hbuf[(size_t)i * 256 + col8 * 8];
        const float aself = expf(eself[head8] - mx[head8]) * inv[head8];
        #pragma unroll
        for (int c = 0; c < 8; c++) acc[c] = (half == 0) ? aself * bs2f(hrs[c]) : 0.f;

        for (int base = start; base < end; base += 64) {
            const int n64 = min(64, end - base);
            const int j = base + lane;
            int sreg = 0;
            if (j < end) {
                sreg = csr[j];
                const f32x4 a = *(const f32x4*)&als[(size_t)sreg * 4];
                f32x4 alpha;
                #pragma unroll
                for (int hh = 0; hh < 4; hh++)
                    alpha[hh] = expf(lrelu(a[hh] + aldv[hh]) - mx[hh]) * inv[hh];
                *(f32x4*)&al_lds[wid][lane][0] = alpha;
            }
            s_lds[wid][lane] = sreg;
            for (int k = half; k < n64; k += 2) {
                const int s = s_lds[wid][k];
                const float a = al_lds[wid][k][head8];
                const u16x8 hr = *(const u16x8*)&hbuf[(size_t)s * 256 + col8 * 8];
                #pragma unroll
                for (int c = 0; c < 8; c++) acc[c] = fmaf(a, bs2f(hr[c]), acc[c]);
            }
        }
    }

    // combine halves, bias + ReLU, 16B store by half 0
    #pragma unroll
    for (int c = 0; c < 8; c++) acc[c] += __shfl_down(acc[c], 32);
    if (half == 0) {
        const f32x4 bv0 = *(const f32x4*)&bias[col8 * 8];
        const f32x4 bv1 = *(const f32x4*)&bias[col8 * 8 + 4];
        u16x8 o;
        #pragma unroll
        for (int c = 0; c < 4; c++) o[c] = f2bs(fmaxf(acc[c] + bv0[c], 0.f));
        #pragma unroll
        for (int c = 4; c < 8; c++) o[c] = f2bs(fmaxf(acc[c] + bv1[c - 4], 0.f));
        *(u16x8*)&act[(size_t)i * 256 + col8 * 8] = o;
    }
}

// ---------------- layer-3 aggregation (H=1, C=32): one wave/node, halves split edges ----
__global__ __launch_bounds__(256) void agg3_kernel(const float* __restrict__ h3,
        const float* __restrict__ als, const float* __restrict__ ald,
        const int* __restrict__ ptr, const int* __restrict__ csr,
        const float* __restrict__ bias, float* __restrict__ out_n, int N) {
    __shared__ float a_lds[4][64];
    __shared__ int   s_lds3[4][64];
    const int t = threadIdx.x, wid = t >> 6, lane = t & 63;
    const int col = lane & 31, half = lane >> 5;
    const int i = blockIdx.x * 4 + wid;
    if (i >= N) return;
    const int start = ptr[i], end = ptr[i + 1];
    const int deg = end - start;
    const float aldv = ald[i];
    const float e0 = lrelu(als[i] + aldv);
    float acc = 0.f;

    if (deg <= 64) {
        // ---- single-pass fast path ----
        int sreg = 0; float ev = -1e30f;
        if (lane < deg) { sreg = csr[start + lane]; ev = lrelu(als[sreg] + aldv); }
        float mx = fmaxf(e0, ev);
        #pragma unroll
        for (int off = 32; off >= 1; off >>= 1) mx = fmaxf(mx, __shfl_xor(mx, off));
        float ex = (lane < deg) ? expf(ev - mx) : 0.f;
        float sm = ex + ((lane == 0) ? expf(e0 - mx) : 0.f);
        #pragma unroll
        for (int off = 32; off >= 1; off >>= 1) sm += __shfl_xor(sm, off);
        const float inv = 1.f / (sm + 1e-16f);
        a_lds[wid][lane] = ex * inv;
        s_lds3[wid][lane] = sreg;
        if (half == 0) acc = expf(e0 - mx) * inv * h3[(size_t)i * 32 + col];

        // halves own alternate edges; 4 loads in flight per half (8/wave)
        int k = half;
        for (; k + 6 < deg; k += 8) {
            const int s0 = s_lds3[wid][k],     s1 = s_lds3[wid][k + 2];
            const int s2 = s_lds3[wid][k + 4], s3 = s_lds3[wid][k + 6];
            const float a0 = a_lds[wid][k],     a1 = a_lds[wid][k + 2];
            const float a2 = a_lds[wid][k + 4], a3 = a_lds[wid][k + 6];
            const float v0 = h3[(size_t)s0 * 32 + col];
            const float v1 = h3[(size_t)s1 * 32 + col];
            const float v2 = h3[(size_t)s2 * 32 + col];
            const float v3 = h3[(size_t)s3 * 32 + col];
            acc = fmaf(a0, v0, acc); acc = fmaf(a1, v1, acc);
            acc = fmaf(a2, v2, acc); acc = fmaf(a3, v3, acc);
        }
        for (; k < deg; k += 2)
            acc = fmaf(a_lds[wid][k], h3[(size_t)s_lds3[wid][k] * 32 + col], acc);
    } else {
        // ---- streaming fallback (rare) ----
        float mx = e0;
        for (int j = start + lane; j < end; j += 64)
            mx = fmaxf(mx, lrelu(als[csr[j]] + aldv));
        #pragma unroll
        for (int off = 32; off >= 1; off >>= 1) mx = fmaxf(mx, __shfl_xor(mx, off));
        float sm = (lane == 0) ? expf(e0 - mx) : 0.f;
        for (int j = start + lane; j < end; j += 64)
            sm += expf(lrelu(als[csr[j]] + aldv) - mx);
        #pragma unroll
        for (int off = 32; off >= 1; off >>= 1) sm += __shfl_xor(sm, off);
        const float inv = 1.f / (sm + 1e-16f);
        if (half == 0) acc = expf(e0 - mx) * inv * h3[(size_t)i * 32 + col];
        for (int base = start; base < end; base += 64) {
            const int n64 = min(64, end - base);
            const int j = base + lane;
            int sreg = 0; float av = 0.f;
            if (j < end) {
                sreg = csr[j];
                av = expf(lrelu(als[sreg] + aldv) - mx) * inv;
            }
            a_lds[wid][lane] = av;
            s_lds3[wid][lane] = sreg;
            for (int k = half; k < n64; k += 2)
                acc = fmaf(a_lds[wid][k], h3[(size_t)s_lds3[wid][k] * 32 + col], acc);
        }
    }

    acc += __shfl_down(acc, 32);
    if (half == 0)
        out_n[(size_t)i * 32 + col] = acc + bias[col];   // no ReLU on layer 3
}

// ---------------- deterministic segmented mean pool (batch sorted) ----------------
__global__ __launch_bounds__(256) void pool_kernel(const float* __restrict__ out_n,
        const int* __restrict__ gstart, float* __restrict__ out, int G) {
    const int t = threadIdx.x, wid = t >> 6, lane = t & 63;
    const int col = lane & 31, half = lane >> 5;
    const int g = blockIdx.x * 4 + wid;
    if (g >= G) return;
    const int s = gstart[g], e = gstart[g + 1];
    float acc = 0.f;
    int r = s + half;
    for (; r + 6 < e; r += 8) {
        acc += out_n[(size_t)r * 32 + col];
        acc += out_n[(size_t)(r + 2) * 32 + col];
        acc += out_n[(size_t)(r + 4) * 32 + col];
        acc += out_n[(size_t)(r + 6) * 32 + col];
    }
    for (; r < e; r += 2) acc += out_n[(size_t)r * 32 + col];
    acc += __shfl_down(acc, 32);
    if (half == 0)
        out[g * 32 + col] = acc / fmaxf((float)(e - s), 1.f);
}

extern "C" void kernel_launch(void* const* d_in, const int* in_sizes, int n_in,
                              void* d_out, int out_size, void* d_ws, size_t ws_size,
                              hipStream_t stream) {
    const int N = 50000, E = 800000, G = 512;
    const float* x    = (const float*)d_in[0];
    const int*   ei   = (const int*)d_in[1];
    const int*   batch= (const int*)d_in[2];
    const float* W1   = (const float*)d_in[3];
    const float* as1  = (const float*)d_in[4];
    const float* ad1  = (const float*)d_in[5];
    const float* b1   = (const float*)d_in[6];
    const float* W2   = (const float*)d_in[7];
    const float* as2  = (const float*)d_in[8];
    const float* ad2  = (const float*)d_in[9];
    const float* b2   = (const float*)d_in[10];
    const float* W3   = (const float*)d_in[11];
    const float* as3  = (const float*)d_in[12];
    const float* ad3  = (const float*)d_in[13];
    const float* b3   = (const float*)d_in[14];
    const int* esrc = ei;
    const int* edst = ei + E;

    char* base = (char*)d_ws; size_t off = 0;
    auto alloc = [&](size_t bytes) -> void* {
        void* p = base + off; off = (off + bytes + 255) & ~(size_t)255; return p;
    };
    u16*   hbuf = (u16*)  alloc((size_t)N * 256 * 2);   // GEMM out / messages (bf16)
    u16*   act  = (u16*)  alloc((size_t)N * 256 * 2);   // bf16 activations
    float* h3   = (float*)alloc((size_t)N * 32 * 4);    // layer-3 pre-agg (fp32)
    float* als  = (float*)alloc((size_t)N * 4 * 4);
    float* ald  = (float*)alloc((size_t)N * 4 * 4);
    int*   deg  = (int*)  alloc((size_t)N * 4);
    int*   ptr  = (int*)  alloc((size_t)(N + 1) * 4);
    int*   cur  = (int*)  alloc((size_t)N * 4);
    int*   csr  = (int*)  alloc((size_t)E * 4);
    u16*   Wt   = (u16*)  alloc((size_t)256 * 800 * 2);
    int*   bsum = (int*)  alloc((size_t)64 * 4);
    float* out_n= (float*)alloc((size_t)N * 32 * 4);    // per-node layer-3 output
    int*   gstart=(int*)  alloc((size_t)(G + 1) * 4);
    float* xtail= (float*)alloc((size_t)N * 32 * 4);    // padded x[:,768:800] (6.4MB)

    hipMemsetAsync(deg, 0, (size_t)N * 4, stream);

    // CSR over dst (reused by all 3 layers; self-loop handled via eself term)
    const int nb = (N + 1023) / 1024;
    deg_kernel<<<(E + 255) / 256, 256, 0, stream>>>(edst, deg, E);
    scan_local<<<nb, 1024, 0, stream>>>(deg, ptr, bsum, N);
    scan_carry<<<1, 64, 0, stream>>>(bsum, nb);
    scan_final<<<nb, 1024, 0, stream>>>(deg, ptr, cur, bsum, N);
    fill_kernel<<<(E + 255) / 256, 256, 0, stream>>>(esrc, edst, cur, csr, E);
    bounds_kernel<<<(N + 256) / 256, 256, 0, stream>>>(batch, gstart, N, G);

    const int gemmGrid = 2 * ((N + 127) / 128);      // 1D; XCD-swizzled in-kernel
    const int aggGrid = (N + 3) / 4;
    // ---- layer 1 (pipelined glds GEMM with fused attention scalars) ----
    transpose_w<<<(256 * 800 + 255) / 256, 256, 0, stream>>>(W1, Wt, 775, 256, 800);
    tail_kernel<<<(N * 32 + 255) / 256, 256, 0, stream>>>(x, xtail, N);
    gemm_glds_f32<<<gemmGrid, 256, 0, stream>>>(x, 775, N, xtail, Wt, 800, hbuf, 256,
                                                as1, ad1, als, ald);
    agg_kernel<<<aggGrid, 256, 0, stream>>>(hbuf, als, ald, ptr, csr, b1, act, N);
    // ---- layer 2 ----
    transpose_w<<<(256 * 256 + 255) / 256, 256, 0, stream>>>(W2, Wt, 256, 256, 256);
    gemm_glds<<<gemmGrid, 256, 0, stream>>>(act, 256, N, 256, Wt, 256, hbuf, 256,
                                            as2, ad2, als, ald);
    agg_kernel<<<aggGrid, 256, 0, stream>>>(hbuf, als, ald, ptr, csr, b2, act, N);
    // ---- layer 3 ----
    transpose_w<<<(32 * 256 + 255) / 256, 256, 0, stream>>>(W3, Wt, 256, 32, 256);
    gemm32<<<(N + 127) / 128, 256, 0, stream>>>(act, 256, N, 256, Wt, 256, h3);
    al3_kernel<<<(N + 7) / 8, 256, 0, stream>>>(h3, as3, ad3, als, ald, N);
    agg3_kernel<<<aggGrid, 256, 0, stream>>>(h3, als, ald, ptr, csr, b3, out_n, N);
    pool_kernel<<<(G + 3) / 4, 256, 0, stream>>>(out_n, gstart, (float*)d_out, G);
}